// Round 3
// baseline (862.589 us; speedup 1.0000x reference)
//
#include <hip/hip_runtime.h>
#include <hip/hip_cooperative_groups.h>

namespace cg = cooperative_groups;

// GCN on 100K nodes / 1.6M edges; output depends only on node_index's 3-hop
// in-neighborhood. v4: single cooperative kernel.
// v3 analysis: 11 dispatches x ~10us launch overhead dominated (device work
// ~30us). v4 fuses all phases into ONE hipLaunchCooperativeKernel with
// grid.sync() between them; persistent blocks re-walk the same edge range
// every scan phase -> dst array is per-XCD-L2-resident after the first scan.
// Host-side occupancy check gates the coop path; fallback = v3 kernels.

#define HID  64
#define CAP1 2048   // compact rows for F2 (layer-1 outputs)
#define CAP2 512    // compact rows for F1 (layer-2 outputs)
#define RB1  128    // per-row in-edge bucket depth, layer 1
#define RB2  128    // per-row in-edge bucket depth, layer 2
#define CL3  2048   // layer-3 edge list capacity
#define VE   8      // edges per thread per scan chunk
#define TPB  256

__device__ __forceinline__ int ld_src(const void* ei, int is64, long long e) {
  return is64 ? (int)((const unsigned*)ei)[e << 1] : ((const int*)ei)[e];
}

// load up to VE dst values starting at edge `base`; returns count
__device__ __forceinline__ int load_dsts(const void* ei, long long E, long long base,
                                         int is64, int d[VE]) {
  int n = (int)((E - base) < VE ? (E - base) : VE);
  if (is64) {
    const unsigned long long* p = (const unsigned long long*)ei + E + base;
    if (n == VE && (((E + base) & 1) == 0)) {
      const ulonglong2* q = (const ulonglong2*)p;
#pragma unroll
      for (int k = 0; k < VE / 2; ++k) {
        ulonglong2 v = q[k];
        d[2 * k] = (int)(unsigned)v.x; d[2 * k + 1] = (int)(unsigned)v.y;
      }
    } else {
      for (int k = 0; k < n; ++k) d[k] = (int)(unsigned)p[k];
    }
  } else {
    const int* p = (const int*)ei + E + base;
    if (n == VE && (((E + base) & 3) == 0)) {
      const int4* q = (const int4*)p;
#pragma unroll
      for (int k = 0; k < VE / 4; ++k) {
        int4 v = q[k];
        d[4 * k] = v.x; d[4 * k + 1] = v.y; d[4 * k + 2] = v.z; d[4 * k + 3] = v.w;
      }
    } else {
      for (int k = 0; k < n; ++k) d[k] = p[k];
    }
  }
  return n;
}

struct GArgs {
  const float* x; const void* ei; const int* nidx;
  const float *W1, *b1, *W2, *b2, *W3, *b3, *Wp, *bp;
  const float *Wa, *ba, *Wm, *bm, *Wg, *bg, *Wt, *bt;
  float* out;
  int N, E;
  int *flag, *cnt1, *cnt2, *ec3;
  int *deg, *need, *slot1, *slot2, *node1, *node2, *rc1, *rc2, *bl1, *bl2, *l3;
  float *h1c, *h2c;
};

__global__ __launch_bounds__(TPB, 4) void k_all(GArgs a) {
  cg::grid_group grid = cg::this_grid();
  const int tid  = blockIdx.x * TPB + threadIdx.x;
  const int gsz  = gridDim.x * TPB;
  const int lane = threadIdx.x & 63;
  const int wv   = threadIdx.x >> 6;

  __shared__ float smA[4][HID];   // l2 row buffer / tail partials
  __shared__ float smB[HID];      // tail g3
  __shared__ float smC[HID];      // tail h3
  __shared__ float smD[HID];      // tail p
  __shared__ int   ssl[64];
  __shared__ float scc[64];
  __shared__ int   s_rows;

  // ---- P0: init (replaces memsets) + dtype detect ----
  for (int i = tid; i < a.N; i += gsz) {
    a.deg[i] = 0; a.need[i] = 0; a.slot1[i] = -1; a.slot2[i] = -1;
  }
  for (int i = tid; i < CAP1; i += gsz) a.rc1[i] = 0;
  for (int i = tid; i < CAP2; i += gsz) a.rc2[i] = 0;
  if (tid == 0) { *a.cnt1 = 0; *a.cnt2 = 0; *a.ec3 = 0; }
  if (tid < 64) {
    const unsigned* e32 = (const unsigned*)a.ei;
    bool z = (e32[2 * tid + 1] == 0u);
    unsigned long long m = __ballot(z);
    if (tid == 0) *a.flag = (m == ~0ull) ? 1 : 0;
  }
  grid.sync();

  const int is64 = *a.flag;
  const int E = a.E;
  const int nidx = *a.nidx;

  // ---- P1: F1 discovery (dst == nidx) + layer-3 edge list ----
  for (long long base = (long long)tid * VE; base < E; base += (long long)gsz * VE) {
    int d[VE]; int n = load_dsts(a.ei, E, base, is64, d);
    for (int k = 0; k < n; ++k) {
      if (d[k] == nidx) {
        int s = ld_src(a.ei, is64, base + k);
        if (atomicCAS(&a.slot2[s], -1, -2) == -1) {
          int p = atomicAdd(a.cnt2, 1) & (CAP2 - 1);
          a.slot2[s] = p; a.node2[p] = s;
        }
        int q = atomicAdd(a.ec3, 1);
        if (q < CL3) a.l3[q] = s;
      }
    }
  }
  grid.sync();

  // ---- P2: seed n0 into F1; propagate F1 -> slot1; mark need (block 0) ----
  if (blockIdx.x == 0) {
    if (threadIdx.x == 0) {
      if (atomicCAS(&a.slot2[nidx], -1, -2) == -1) {
        int p = atomicAdd(a.cnt2, 1) & (CAP2 - 1);
        a.slot2[nidx] = p; a.node2[p] = nidx;
      }
      s_rows = min(*a.cnt2, CAP2);
    }
    __syncthreads();
    for (int r = threadIdx.x; r < s_rows; r += TPB) {
      int i = a.node2[r];
      a.need[i] = 1;
      if (atomicCAS(&a.slot1[i], -1, -2) == -1) {
        int p = atomicAdd(a.cnt1, 1) & (CAP1 - 1);
        a.slot1[i] = p; a.node1[p] = i;
      }
    }
  }
  grid.sync();

  // ---- P3: F2 discovery (dst in F1): claim slot1, mark need, bucket bl2 ----
  for (long long base = (long long)tid * VE; base < E; base += (long long)gsz * VE) {
    int d[VE]; int n = load_dsts(a.ei, E, base, is64, d);
    for (int k = 0; k < n; ++k) {
      int ad = a.slot2[d[k]];
      if (ad >= 0) {
        int s = ld_src(a.ei, is64, base + k);
        a.need[s] = 1;
        if (atomicCAS(&a.slot1[s], -1, -2) == -1) {
          int p = atomicAdd(a.cnt1, 1) & (CAP1 - 1);
          a.slot1[s] = p; a.node1[p] = s;
        }
        int q = atomicAdd(&a.rc2[ad], 1);
        if (q < RB2) a.bl2[ad * RB2 + q] = s;
      }
    }
  }
  grid.sync();

  // ---- P4: S marking + layer-1 buckets (dst in F2) ----
  for (long long base = (long long)tid * VE; base < E; base += (long long)gsz * VE) {
    int d[VE]; int n = load_dsts(a.ei, E, base, is64, d);
    for (int k = 0; k < n; ++k) {
      int ad = a.slot1[d[k]];
      if (ad >= 0) {
        int s = ld_src(a.ei, is64, base + k);
        a.need[s] = 1;
        int q = atomicAdd(&a.rc1[ad], 1);
        if (q < RB1) a.bl1[ad * RB1 + q] = s;
      }
    }
  }
  grid.sync();

  // ---- P5: need-filtered degree histogram ----
  for (long long base = (long long)tid * VE; base < E; base += (long long)gsz * VE) {
    int d[VE]; int n = load_dsts(a.ei, E, base, is64, d);
    for (int k = 0; k < n; ++k)
      if (a.need[d[k]]) atomicAdd(&a.deg[d[k]], 1);
  }
  grid.sync();

  // ---- P6: layer 1, one wave per F2 row (factorized) ----
  {
    int rows = min(*a.cnt1, CAP1);
    int wid = tid >> 6, nw = gsz >> 6;
    for (int w = wid; w < rows; w += nw) {
      int i = a.node1[w];
      float di = 1.0f / sqrtf((float)(a.deg[i] + 1));
      int cnt = min(a.rc1[w], RB1);
      float ax = 0.f, ay = 0.f, az = 0.f, aw = 0.f;
      for (int j = lane; j < cnt; j += 64) {
        int s = a.bl1[w * RB1 + j];
        float c = (1.0f / sqrtf((float)(a.deg[s] + 1))) * di;
        float4 xv = ((const float4*)a.x)[s];
        ax += c * xv.x; ay += c * xv.y; az += c * xv.z; aw += c * xv.w;
      }
#pragma unroll
      for (int t = 1; t < 64; t <<= 1) {
        ax += __shfl_xor(ax, t); ay += __shfl_xor(ay, t);
        az += __shfl_xor(az, t); aw += __shfl_xor(aw, t);
      }
      float4 xi = ((const float4*)a.x)[i];
      float dd = di * di;
      ax += dd * xi.x; ay += dd * xi.y; az += dd * xi.z; aw += dd * xi.w;
      float v = ax * a.W1[lane] + ay * a.W1[64 + lane] + az * a.W1[128 + lane] +
                aw * a.W1[192 + lane] + a.b1[lane];
      a.h1c[w * HID + lane] = v > 0.f ? v : 0.f;
    }
  }
  grid.sync();

  // ---- P7: layer 2, one wave per F1 row ----
  {
    int rows = min(*a.cnt2, CAP2);
    int wid = tid >> 6, nw = gsz >> 6;
    for (int w = wid; w < rows; w += nw) {
      int i = a.node2[w];
      float di = 1.0f / sqrtf((float)(a.deg[i] + 1));
      int cnt = min(a.rc2[w], RB2);
      float acc = 0.f;
      for (int j0 = 0; j0 < cnt; j0 += 64) {
        int nb = min(64, cnt - j0);
        int sl = 0; float c = 0.f;
        if (lane < nb) {
          int s = a.bl2[w * RB2 + j0 + lane];
          sl = a.slot1[s];
          c = (1.0f / sqrtf((float)(a.deg[s] + 1))) * di;
        }
        for (int j = 0; j < nb; ++j) {
          int slj = __shfl(sl, j);
          float cj = __shfl(c, j);
          acc += cj * a.h1c[slj * HID + lane];
        }
      }
      acc += di * di * a.h1c[a.slot1[i] * HID + lane];
      smA[wv][lane] = acc;  // same-wave write->read (lockstep)
      float v = a.b2[lane];
#pragma unroll 16
      for (int k = 0; k < HID; ++k) v += smA[wv][k] * a.W2[k * HID + lane];
      a.h2c[w * HID + lane] = v > 0.f ? v : 0.f;
    }
  }
  grid.sync();

  // ---- P8: layer-3 aggregate + head MLP + 4 projections (block 0) ----
  if (blockIdx.x == 0) {
    int t = threadIdx.x;
    float dn = 1.0f / sqrtf((float)(a.deg[nidx] + 1));
    int cnt = min(*a.ec3, CL3);
    float acc = 0.f;
    for (int j0 = 0; j0 < cnt; j0 += 64) {
      int nb = min(64, cnt - j0);
      if (t < nb) {
        int s = a.l3[j0 + t];
        ssl[t] = a.slot2[s];
        scc[t] = (1.0f / sqrtf((float)(a.deg[s] + 1))) * dn;
      }
      __syncthreads();
      for (int j = wv; j < nb; j += 4)
        acc += scc[j] * a.h2c[ssl[j] * HID + lane];
      __syncthreads();
    }
    smA[wv][lane] = acc;
    __syncthreads();
    if (wv == 0) {
      float s = smA[0][lane] + smA[1][lane] + smA[2][lane] + smA[3][lane];
      s += dn * dn * a.h2c[a.slot2[nidx] * HID + lane];
      smB[lane] = s;
    }
    __syncthreads();
    if (wv == 0) {
      float v = a.b3[lane];
#pragma unroll 16
      for (int k = 0; k < HID; ++k) v += smB[k] * a.W3[k * HID + lane];
      smC[lane] = v > 0.f ? v : 0.f;
    }
    __syncthreads();
    if (wv == 0) {
      float pv = a.bp[lane];
#pragma unroll 16
      for (int k = 0; k < HID; ++k) pv += smC[k] * a.Wp[k * HID + lane];
      smD[lane] = pv > 0.f ? pv : 0.f;
    }
    __syncthreads();
    if (t < 4) {
      float o = a.ba[t];
      for (int k = 0; k < HID; ++k) o += smD[k] * a.Wa[k * 4 + t];
      a.out[t] = o;
    } else if (t < 6) {
      int c = t - 4; float o = a.bm[c];
      for (int k = 0; k < HID; ++k) o += smD[k] * a.Wm[k * 2 + c];
      a.out[t] = o;
    } else if (t < 9) {
      int c = t - 6; float o = a.bg[c];
      for (int k = 0; k < HID; ++k) o += smD[k] * a.Wg[k * 3 + c];
      a.out[t] = o;
    } else if (t < 19) {
      int c = t - 9; float o = a.bt[c];
      for (int k = 0; k < HID; ++k) o += smD[k] * a.Wt[k * 10 + c];
      a.out[t] = o;
    }
  }
}

// ======================= fallback path (v3, verified) =======================

__global__ void k_detect(const unsigned* e32, int* flag) {
  if (blockIdx.x == 0 && threadIdx.x == 0) {
    int is64 = 1;
    for (int k = 0; k < 64; ++k)
      if (e32[2 * k + 1] != 0u) { is64 = 0; break; }
    *flag = is64;
  }
}

__global__ void k_scanF1(const void* ei, int E, const int* flag, const int* nidx_p,
                         int* slot2, int* node2, int* cnt2, int* l3, int* ec3) {
  long long base = ((long long)blockIdx.x * blockDim.x + threadIdx.x) * VE;
  if (base >= E) return;
  int is64 = *flag, nidx = *nidx_p;
  int d[VE];
  int n = load_dsts(ei, E, base, is64, d);
  for (int k = 0; k < n; ++k) {
    if (d[k] == nidx) {
      int s = ld_src(ei, is64, base + k);
      if (atomicCAS(&slot2[s], -1, -2) == -1) {
        int p = atomicAdd(cnt2, 1) & (CAP2 - 1);
        slot2[s] = p; node2[p] = s;
      }
      int q = atomicAdd(ec3, 1);
      if (q < CL3) l3[q] = s;
    }
  }
}

__global__ void k_seed(const int* nidx_p, int* slot1, int* slot2,
                       int* node1, int* node2, int* need, int* cnt1, int* cnt2) {
  __shared__ int rows;
  if (threadIdx.x == 0) {
    int n = *nidx_p;
    if (atomicCAS(&slot2[n], -1, -2) == -1) {
      int p = atomicAdd(cnt2, 1) & (CAP2 - 1);
      slot2[n] = p; node2[p] = n;
    }
    rows = min(*cnt2, CAP2);
  }
  __syncthreads();
  for (int r = threadIdx.x; r < rows; r += blockDim.x) {
    int i = node2[r];
    need[i] = 1;
    if (atomicCAS(&slot1[i], -1, -2) == -1) {
      int p = atomicAdd(cnt1, 1) & (CAP1 - 1);
      slot1[i] = p; node1[p] = i;
    }
  }
}

__global__ void k_scanF2(const void* ei, int E, const int* flag,
                         const int* slot2, int* slot1, int* node1, int* need,
                         int* cnt1, int* rc2, int* bl2) {
  long long base = ((long long)blockIdx.x * blockDim.x + threadIdx.x) * VE;
  if (base >= E) return;
  int is64 = *flag;
  int d[VE];
  int n = load_dsts(ei, E, base, is64, d);
  for (int k = 0; k < n; ++k) {
    int ad = slot2[d[k]];
    if (ad >= 0) {
      int s = ld_src(ei, is64, base + k);
      need[s] = 1;
      if (atomicCAS(&slot1[s], -1, -2) == -1) {
        int p = atomicAdd(cnt1, 1) & (CAP1 - 1);
        slot1[s] = p; node1[p] = s;
      }
      int q = atomicAdd(&rc2[ad], 1);
      if (q < RB2) bl2[ad * RB2 + q] = s;
    }
  }
}

__global__ void k_scanS(const void* ei, int E, const int* flag,
                        const int* slot1, int* need, int* rc1, int* bl1) {
  long long base = ((long long)blockIdx.x * blockDim.x + threadIdx.x) * VE;
  if (base >= E) return;
  int is64 = *flag;
  int d[VE];
  int n = load_dsts(ei, E, base, is64, d);
  for (int k = 0; k < n; ++k) {
    int ad = slot1[d[k]];
    if (ad >= 0) {
      int s = ld_src(ei, is64, base + k);
      need[s] = 1;
      int q = atomicAdd(&rc1[ad], 1);
      if (q < RB1) bl1[ad * RB1 + q] = s;
    }
  }
}

__global__ void k_scanDeg(const void* ei, int E, const int* flag,
                          const int* need, int* deg) {
  long long base = ((long long)blockIdx.x * blockDim.x + threadIdx.x) * VE;
  if (base >= E) return;
  int is64 = *flag;
  int d[VE];
  int n = load_dsts(ei, E, base, is64, d);
  for (int k = 0; k < n; ++k)
    if (need[d[k]]) atomicAdd(&deg[d[k]], 1);
}

__global__ void k_l1(const float* __restrict__ x, const float* __restrict__ W1,
                     const float* __restrict__ b1, const int* __restrict__ deg,
                     const int* __restrict__ node1, const int* __restrict__ cnt1,
                     const int* __restrict__ rc1, const int* __restrict__ bl1,
                     float* __restrict__ h1c) {
  int w = blockIdx.x * 4 + (threadIdx.x >> 6);
  int lane = threadIdx.x & 63;
  int rows = min(*cnt1, CAP1);
  if (w >= rows) return;
  int i = node1[w];
  float di = 1.0f / sqrtf((float)(deg[i] + 1));
  int cnt = min(rc1[w], RB1);
  float ax = 0.f, ay = 0.f, az = 0.f, aw = 0.f;
  for (int j = lane; j < cnt; j += 64) {
    int s = bl1[w * RB1 + j];
    float c = (1.0f / sqrtf((float)(deg[s] + 1))) * di;
    float4 xv = ((const float4*)x)[s];
    ax += c * xv.x; ay += c * xv.y; az += c * xv.z; aw += c * xv.w;
  }
#pragma unroll
  for (int t = 1; t < 64; t <<= 1) {
    ax += __shfl_xor(ax, t); ay += __shfl_xor(ay, t);
    az += __shfl_xor(az, t); aw += __shfl_xor(aw, t);
  }
  float4 xi = ((const float4*)x)[i];
  float dd = di * di;
  ax += dd * xi.x; ay += dd * xi.y; az += dd * xi.z; aw += dd * xi.w;
  float v = ax * W1[lane] + ay * W1[64 + lane] + az * W1[128 + lane] +
            aw * W1[192 + lane] + b1[lane];
  h1c[w * HID + lane] = v > 0.f ? v : 0.f;
}

__global__ void k_l2(const float* __restrict__ W2, const float* __restrict__ b2,
                     const int* __restrict__ deg, const int* __restrict__ node2,
                     const int* __restrict__ cnt2, const int* __restrict__ slot1,
                     const int* __restrict__ rc2, const int* __restrict__ bl2,
                     const float* __restrict__ h1c, float* __restrict__ h2c) {
  __shared__ float sh[4][HID];
  int wv = threadIdx.x >> 6, lane = threadIdx.x & 63;
  int w = blockIdx.x * 4 + wv;
  int rows = min(*cnt2, CAP2);
  if (w >= rows) return;
  int i = node2[w];
  float di = 1.0f / sqrtf((float)(deg[i] + 1));
  int cnt = min(rc2[w], RB2);
  float acc = 0.f;
  for (int j0 = 0; j0 < cnt; j0 += 64) {
    int nb = min(64, cnt - j0);
    int sl = 0; float c = 0.f;
    if (lane < nb) {
      int s = bl2[w * RB2 + j0 + lane];
      sl = slot1[s];
      c = (1.0f / sqrtf((float)(deg[s] + 1))) * di;
    }
    for (int j = 0; j < nb; ++j) {
      int slj = __shfl(sl, j);
      float cj = __shfl(c, j);
      acc += cj * h1c[slj * HID + lane];
    }
  }
  acc += di * di * h1c[slot1[i] * HID + lane];
  sh[wv][lane] = acc;
  float v = b2[lane];
#pragma unroll 16
  for (int k = 0; k < HID; ++k) v += sh[wv][k] * W2[k * HID + lane];
  h2c[w * HID + lane] = v > 0.f ? v : 0.f;
}

__global__ void k_tail(const int* nidx_p, const int* slot2, const int* deg,
                       const float* h2c, const int* l3, const int* ec3,
                       const float* W3, const float* b3,
                       const float* Wp, const float* bp,
                       const float* Wa, const float* ba,
                       const float* Wm, const float* bm,
                       const float* Wg, const float* bg,
                       const float* Wt, const float* bt, float* out) {
  __shared__ float part[4][HID];
  __shared__ float g3[HID];
  __shared__ float h3[HID];
  __shared__ float p[HID];
  __shared__ int   ssl[64];
  __shared__ float scc[64];
  int tid = threadIdx.x, wv = tid >> 6, lane = tid & 63;
  int nidx = *nidx_p;
  float dn = 1.0f / sqrtf((float)(deg[nidx] + 1));
  int cnt = min(*ec3, CL3);
  float acc = 0.f;
  for (int j0 = 0; j0 < cnt; j0 += 64) {
    int nb = min(64, cnt - j0);
    if (tid < nb) {
      int s = l3[j0 + tid];
      ssl[tid] = slot2[s];
      scc[tid] = (1.0f / sqrtf((float)(deg[s] + 1))) * dn;
    }
    __syncthreads();
    for (int j = wv; j < nb; j += 4)
      acc += scc[j] * h2c[ssl[j] * HID + lane];
    __syncthreads();
  }
  part[wv][lane] = acc;
  __syncthreads();
  if (wv == 0) {
    float a = part[0][lane] + part[1][lane] + part[2][lane] + part[3][lane];
    a += dn * dn * h2c[slot2[nidx] * HID + lane];
    g3[lane] = a;
  }
  __syncthreads();
  if (wv == 0) {
    float v = b3[lane];
#pragma unroll 16
    for (int k = 0; k < HID; ++k) v += g3[k] * W3[k * HID + lane];
    h3[lane] = v > 0.f ? v : 0.f;
  }
  __syncthreads();
  if (wv == 0) {
    float pv = bp[lane];
#pragma unroll 16
    for (int k = 0; k < HID; ++k) pv += h3[k] * Wp[k * HID + lane];
    p[lane] = pv > 0.f ? pv : 0.f;
  }
  __syncthreads();
  if (tid < 4) {
    float o = ba[tid];
    for (int k = 0; k < HID; ++k) o += p[k] * Wa[k * 4 + tid];
    out[tid] = o;
  } else if (tid < 6) {
    int c = tid - 4; float o = bm[c];
    for (int k = 0; k < HID; ++k) o += p[k] * Wm[k * 2 + c];
    out[tid] = o;
  } else if (tid < 9) {
    int c = tid - 6; float o = bg[c];
    for (int k = 0; k < HID; ++k) o += p[k] * Wg[k * 3 + c];
    out[tid] = o;
  } else if (tid < 19) {
    int c = tid - 9; float o = bt[c];
    for (int k = 0; k < HID; ++k) o += p[k] * Wt[k * 10 + c];
    out[tid] = o;
  }
}

// ============================================================================

extern "C" void kernel_launch(void* const* d_in, const int* in_sizes, int n_in,
                              void* d_out, int out_size, void* d_ws, size_t ws_size,
                              hipStream_t stream) {
  const float* x  = (const float*)d_in[0];
  const void*  ei = d_in[1];
  const int* nidx = (const int*)d_in[2];
  const float* W1 = (const float*)d_in[3];
  const float* b1 = (const float*)d_in[4];
  const float* W2 = (const float*)d_in[5];
  const float* b2 = (const float*)d_in[6];
  const float* W3 = (const float*)d_in[7];
  const float* b3 = (const float*)d_in[8];
  const float* Wp = (const float*)d_in[9];
  const float* bp = (const float*)d_in[10];
  const float* Wa = (const float*)d_in[11];
  const float* ba = (const float*)d_in[12];
  const float* Wm = (const float*)d_in[13];
  const float* bm = (const float*)d_in[14];
  const float* Wg = (const float*)d_in[15];
  const float* bg = (const float*)d_in[16];
  const float* Wt = (const float*)d_in[17];
  const float* bt = (const float*)d_in[18];
  float* out = (float*)d_out;

  int N = in_sizes[0] / 4;   // 100000
  int E = in_sizes[1] / 2;   // 1600000

  char* w = (char*)d_ws;
  size_t o = 0;
  auto take = [&](size_t bytes) -> void* {
    void* p = w + o;
    o += (bytes + 255) & ~(size_t)255;
    return p;
  };
  size_t zeroBytes = (size_t)(3 + 2 * N + CAP1 + CAP2) * 4;
  int* zr = (int*)take(zeroBytes);
  int* cnt1 = zr + 0;
  int* cnt2 = zr + 1;
  int* ec3  = zr + 2;
  int* deg  = zr + 3;
  int* need = deg + N;
  int* rc1  = need + N;
  int* rc2  = rc1 + CAP1;
  int* slots = (int*)take((size_t)2 * N * 4);
  int* slot1 = slots;
  int* slot2 = slots + N;
  int*   flag  = (int*)take(4);
  int*   node1 = (int*)take((size_t)CAP1 * 4);
  int*   node2 = (int*)take((size_t)CAP2 * 4);
  int*   bl1   = (int*)take((size_t)CAP1 * RB1 * 4);
  int*   bl2   = (int*)take((size_t)CAP2 * RB2 * 4);
  int*   l3    = (int*)take((size_t)CL3 * 4);
  float* h1c   = (float*)take((size_t)CAP1 * HID * 4);
  float* h2c   = (float*)take((size_t)CAP2 * HID * 4);

  // one-time deterministic decision: cooperative path only if the grid is
  // guaranteed co-resident (occupancy query is host-side, capture-safe).
  static int s_grid = 0;
  static int s_coop = -1;
  if (s_coop < 0) {
    int dev = 0; hipGetDevice(&dev);
    int coopAttr = 0;
    hipDeviceGetAttribute(&coopAttr, hipDeviceAttributeCooperativeLaunch, dev);
    int cus = 0;
    hipDeviceGetAttribute(&cus, hipDeviceAttributeMultiprocessorCount, dev);
    int perCU = 0;
    hipError_t oe = hipOccupancyMaxActiveBlocksPerMultiprocessor(
        &perCU, (const void*)k_all, TPB, 0);
    int g = (oe == hipSuccess) ? perCU * cus : 0;
    if (g > 1024) g = 1024;
    s_grid = g;
    s_coop = (coopAttr && g >= 64) ? 1 : 0;
  }

  if (s_coop == 1) {
    GArgs a;
    a.x = x; a.ei = ei; a.nidx = nidx;
    a.W1 = W1; a.b1 = b1; a.W2 = W2; a.b2 = b2; a.W3 = W3; a.b3 = b3;
    a.Wp = Wp; a.bp = bp; a.Wa = Wa; a.ba = ba; a.Wm = Wm; a.bm = bm;
    a.Wg = Wg; a.bg = bg; a.Wt = Wt; a.bt = bt;
    a.out = out; a.N = N; a.E = E;
    a.flag = flag; a.cnt1 = cnt1; a.cnt2 = cnt2; a.ec3 = ec3;
    a.deg = deg; a.need = need; a.slot1 = slot1; a.slot2 = slot2;
    a.node1 = node1; a.node2 = node2; a.rc1 = rc1; a.rc2 = rc2;
    a.bl1 = bl1; a.bl2 = bl2; a.l3 = l3; a.h1c = h1c; a.h2c = h2c;
    void* params[] = { (void*)&a };
    hipLaunchCooperativeKernel((const void*)k_all, dim3(s_grid), dim3(TPB),
                               params, 0, stream);
    return;
  }

  // fallback: v3 multi-kernel path
  int gS = (int)(((long long)E + TPB * VE - 1) / (TPB * VE));
  hipMemsetAsync(zr, 0x00, zeroBytes, stream);
  hipMemsetAsync(slots, 0xFF, (size_t)2 * N * 4, stream);
  k_detect <<<1, 64, 0, stream>>>((const unsigned*)ei, flag);
  k_scanF1 <<<gS, TPB, 0, stream>>>(ei, E, flag, nidx, slot2, node2, cnt2, l3, ec3);
  k_seed   <<<1, TPB, 0, stream>>>(nidx, slot1, slot2, node1, node2, need, cnt1, cnt2);
  k_scanF2 <<<gS, TPB, 0, stream>>>(ei, E, flag, slot2, slot1, node1, need, cnt1, rc2, bl2);
  k_scanS  <<<gS, TPB, 0, stream>>>(ei, E, flag, slot1, need, rc1, bl1);
  k_scanDeg<<<gS, TPB, 0, stream>>>(ei, E, flag, need, deg);
  k_l1     <<<CAP1 / 4, TPB, 0, stream>>>(x, W1, b1, deg, node1, cnt1, rc1, bl1, h1c);
  k_l2     <<<CAP2 / 4, TPB, 0, stream>>>(W2, b2, deg, node2, cnt2, slot1, rc2, bl2, h1c, h2c);
  k_tail   <<<1, TPB, 0, stream>>>(nidx, slot2, deg, h2c, l3, ec3, W3, b3, Wp, bp,
                                   Wa, ba, Wm, bm, Wg, bg, Wt, bt, out);
}

// Round 4
// 194.308 us; speedup vs baseline: 4.4393x; 4.4393x over previous
//
#include <hip/hip_runtime.h>

// GCN on 100K nodes / 1.6M edges; output depends only on node_index's 3-hop
// in-neighborhood. v5: v3 multi-kernel structure (v4's cooperative grid.sync
// fusion was a 5x regression: barrier cost + phase stragglers), minus 3
// dispatches, minus half the scan read traffic.
//   F1 = in(n0) u {n0}   (~17)   -> rows node2/slot2
//   F2 = in(F1) u F1     (~290)  -> rows node1/slot1
//   S  = F2 u in(F2)     (~5K)   -> need[]: nodes whose degree we must count
// Changes vs v3 (165us):
//  - k_detect folded into scans (per-wave probe: 1 load + ballot).
//  - k_seed folded into scanF1 (n0 seed) + scanF2 prologue (F1->slot1+need;
//    CAS dedups across blocks; slot1 VALUES are never read inside scanF2).
//  - scanF1 compacts dst low-dwords into dst32[E] (6.4 MB); scans 2-4 read
//    that (half the bytes, int4 loads); scanDeg no longer touches ei.
//  - k_l2 + k_tail fused into one single-block kernel, h2 rows in LDS.
// 8 dispatches total (2 memsets + 6 kernels).

#define HID  64
#define CAP1 2048   // compact rows for F2 (layer-1 outputs)
#define CAP2 512    // compact rows for F1 (layer-2 outputs)
#define RB1  128    // per-row in-edge bucket depth, layer 1
#define RB2  128    // per-row in-edge bucket depth, layer 2
#define CL3  2048   // layer-3 edge list capacity
#define VE   8      // edges per thread in scans
#define TPB  256

// wave-level dtype probe: high dwords of first 64 entries all zero -> int64
__device__ __forceinline__ int detect64(const void* ei) {
  const unsigned* e32 = (const unsigned*)ei;
  int lane = threadIdx.x & 63;
  bool z = (e32[2 * lane + 1] == 0u);
  return (__ballot(z) == ~0ull) ? 1 : 0;
}

__device__ __forceinline__ int ld_src(const void* ei, int is64, long long e) {
  return is64 ? (int)((const unsigned*)ei)[e << 1] : ((const int*)ei)[e];
}

// load up to VE dst values from the raw edge index (scanF1 only)
__device__ __forceinline__ int load_dsts(const void* ei, long long E, long long base,
                                         int is64, int d[VE]) {
  int n = (int)((E - base) < VE ? (E - base) : VE);
  if (is64) {
    const unsigned long long* p = (const unsigned long long*)ei + E + base;
    if (n == VE && (((E + base) & 1) == 0)) {
      const ulonglong2* q = (const ulonglong2*)p;
#pragma unroll
      for (int k = 0; k < VE / 2; ++k) {
        ulonglong2 v = q[k];
        d[2 * k] = (int)(unsigned)v.x; d[2 * k + 1] = (int)(unsigned)v.y;
      }
    } else {
      for (int k = 0; k < n; ++k) d[k] = (int)(unsigned)p[k];
    }
  } else {
    const int* p = (const int*)ei + E + base;
    if (n == VE && (((E + base) & 3) == 0)) {
      const int4* q = (const int4*)p;
#pragma unroll
      for (int k = 0; k < VE / 4; ++k) {
        int4 v = q[k];
        d[4 * k] = v.x; d[4 * k + 1] = v.y; d[4 * k + 2] = v.z; d[4 * k + 3] = v.w;
      }
    } else {
      for (int k = 0; k < n; ++k) d[k] = p[k];
    }
  }
  return n;
}

// load up to VE dst values from the compacted int32 array (scans 2-4)
__device__ __forceinline__ int load_dsts32(const int* dst32, long long E,
                                           long long base, int d[VE]) {
  int n = (int)((E - base) < VE ? (E - base) : VE);
  if (n == VE) {  // base is a multiple of VE -> 16B aligned
    int4 a = ((const int4*)(dst32 + base))[0];
    int4 b = ((const int4*)(dst32 + base))[1];
    d[0] = a.x; d[1] = a.y; d[2] = a.z; d[3] = a.w;
    d[4] = b.x; d[5] = b.y; d[6] = b.z; d[7] = b.w;
  } else {
    for (int k = 0; k < n; ++k) d[k] = dst32[base + k];
  }
  return n;
}

// F1 discovery (dst == n0) + n0 seeding + dst32 compaction + layer-3 list.
__global__ void k_scanF1(const void* ei, int E, const int* nidx_p, int* dst32,
                         int* slot2, int* node2, int* cnt2, int* l3, int* ec3) {
  int is64 = detect64(ei);
  int nidx = *nidx_p;
  if (blockIdx.x == 0 && threadIdx.x == 0) {  // seed n0 into F1 (CAS-safe)
    if (atomicCAS(&slot2[nidx], -1, -2) == -1) {
      int p = atomicAdd(cnt2, 1) & (CAP2 - 1);
      slot2[nidx] = p; node2[p] = nidx;
    }
  }
  long long base = ((long long)blockIdx.x * TPB + threadIdx.x) * VE;
  if (base >= E) return;
  int d[VE];
  int n = load_dsts(ei, E, base, is64, d);
  if (n == VE) {
    ((int4*)(dst32 + base))[0] = make_int4(d[0], d[1], d[2], d[3]);
    ((int4*)(dst32 + base))[1] = make_int4(d[4], d[5], d[6], d[7]);
  } else {
    for (int k = 0; k < n; ++k) dst32[base + k] = d[k];
  }
  for (int k = 0; k < n; ++k) {
    if (d[k] == nidx) {
      int s = ld_src(ei, is64, base + k);
      if (atomicCAS(&slot2[s], -1, -2) == -1) {
        int p = atomicAdd(cnt2, 1) & (CAP2 - 1);
        slot2[s] = p; node2[p] = s;
      }
      int q = atomicAdd(ec3, 1);
      if (q < CL3) l3[q] = s;
    }
  }
}

// F2 discovery: prologue propagates F1 -> slot1 (+need); main loop claims
// sources of F1-dst edges and buckets them per F1 row. slot1 values are
// never READ here, so concurrent CAS claims across blocks are safe.
__global__ void k_scanF2(const void* ei, int E, const int* dst32,
                         const int* slot2, const int* node2, const int* cnt2,
                         int* slot1, int* node1, int* need, int* cnt1,
                         int* rc2, int* bl2) {
  int rows2 = min(*cnt2, CAP2);
  for (int r = threadIdx.x; r < rows2; r += TPB) {
    int i = node2[r];
    need[i] = 1;
    if (atomicCAS(&slot1[i], -1, -2) == -1) {
      int p = atomicAdd(cnt1, 1) & (CAP1 - 1);
      slot1[i] = p; node1[p] = i;
    }
  }
  int is64 = detect64(ei);
  long long base = ((long long)blockIdx.x * TPB + threadIdx.x) * VE;
  if (base >= E) return;
  int d[VE];
  int n = load_dsts32(dst32, E, base, d);
  for (int k = 0; k < n; ++k) {
    int ad = slot2[d[k]];
    if (ad >= 0) {
      int s = ld_src(ei, is64, base + k);
      need[s] = 1;
      if (atomicCAS(&slot1[s], -1, -2) == -1) {
        int p = atomicAdd(cnt1, 1) & (CAP1 - 1);
        slot1[s] = p; node1[p] = s;
      }
      int q = atomicAdd(&rc2[ad], 1);
      if (q < RB2) bl2[ad * RB2 + q] = s;
    }
  }
}

// S marking + layer-1 buckets: edges with dst in F2.
__global__ void k_scanS(const void* ei, int E, const int* dst32,
                        const int* slot1, int* need, int* rc1, int* bl1) {
  int is64 = detect64(ei);
  long long base = ((long long)blockIdx.x * TPB + threadIdx.x) * VE;
  if (base >= E) return;
  int d[VE];
  int n = load_dsts32(dst32, E, base, d);
  for (int k = 0; k < n; ++k) {
    int ad = slot1[d[k]];
    if (ad >= 0) {
      int s = ld_src(ei, is64, base + k);
      need[s] = 1;
      int q = atomicAdd(&rc1[ad], 1);
      if (q < RB1) bl1[ad * RB1 + q] = s;
    }
  }
}

// need-filtered degree histogram (~80K atomics over ~5K addresses)
__global__ void k_scanDeg(int E, const int* dst32, const int* need, int* deg) {
  long long base = ((long long)blockIdx.x * TPB + threadIdx.x) * VE;
  if (base >= E) return;
  int d[VE];
  int n = load_dsts32(dst32, E, base, d);
  for (int k = 0; k < n; ++k)
    if (need[d[k]]) atomicAdd(&deg[d[k]], 1);
}

// layer 1, one wave per F2 row (factorized: neighbor-sum then one matvec).
__global__ void k_l1(const float* __restrict__ x, const float* __restrict__ W1,
                     const float* __restrict__ b1, const int* __restrict__ deg,
                     const int* __restrict__ node1, const int* __restrict__ cnt1,
                     const int* __restrict__ rc1, const int* __restrict__ bl1,
                     float* __restrict__ h1c) {
  int w = blockIdx.x * 4 + (threadIdx.x >> 6);
  int lane = threadIdx.x & 63;
  int rows = min(*cnt1, CAP1);
  if (w >= rows) return;
  int i = node1[w];
  float di = 1.0f / sqrtf((float)(deg[i] + 1));
  int cnt = min(rc1[w], RB1);
  float ax = 0.f, ay = 0.f, az = 0.f, aw = 0.f;
  for (int j = lane; j < cnt; j += 64) {
    int s = bl1[w * RB1 + j];
    float c = (1.0f / sqrtf((float)(deg[s] + 1))) * di;
    float4 xv = ((const float4*)x)[s];
    ax += c * xv.x; ay += c * xv.y; az += c * xv.z; aw += c * xv.w;
  }
#pragma unroll
  for (int t = 1; t < 64; t <<= 1) {
    ax += __shfl_xor(ax, t); ay += __shfl_xor(ay, t);
    az += __shfl_xor(az, t); aw += __shfl_xor(aw, t);
  }
  float4 xi = ((const float4*)x)[i];
  float dd = di * di;
  ax += dd * xi.x; ay += dd * xi.y; az += dd * xi.z; aw += dd * xi.w;
  float v = ax * W1[lane] + ay * W1[64 + lane] + az * W1[128 + lane] +
            aw * W1[192 + lane] + b1[lane];
  h1c[w * HID + lane] = v > 0.f ? v : 0.f;
}

// fused layer-2 + layer-3 + head. One block, 256 threads (4 waves).
// Phase A: one wave per F1 row, h2 rows kept in LDS (spill to global >=64).
// Phase B: layer-3 aggregate over l3 list + MLP + 4 projections.
__global__ __launch_bounds__(TPB) void k_l2tail(
    const float* W2, const float* b2, const int* deg,
    const int* node2, const int* cnt2, const int* slot1,
    const int* rc2, const int* bl2, const float* h1c, float* h2c,
    const int* nidx_p, const int* slot2, const int* l3, const int* ec3,
    const float* W3, const float* b3, const float* Wp, const float* bp,
    const float* Wa, const float* ba, const float* Wm, const float* bm,
    const float* Wg, const float* bg, const float* Wt, const float* bt,
    float* out) {
  __shared__ float h2s[64][HID];
  __shared__ float smA[4][HID];
  __shared__ float g3[HID];
  __shared__ float h3v[HID];
  __shared__ float pj[HID];
  __shared__ int   ssl[64];
  __shared__ float scc[64];
  int tid = threadIdx.x, wv = tid >> 6, lane = tid & 63;
  int nidx = *nidx_p;
  int rows = min(*cnt2, CAP2);

  for (int w = wv; w < rows; w += 4) {
    int i = node2[w];
    float di = 1.0f / sqrtf((float)(deg[i] + 1));
    int cnt = min(rc2[w], RB2);
    float acc = 0.f;
    for (int j0 = 0; j0 < cnt; j0 += 64) {
      int nb = min(64, cnt - j0);
      int sl = 0; float c = 0.f;
      if (lane < nb) {
        int s = bl2[w * RB2 + j0 + lane];
        sl = slot1[s];
        c = (1.0f / sqrtf((float)(deg[s] + 1))) * di;
      }
      for (int j = 0; j < nb; ++j)
        acc += __shfl(c, j) * h1c[__shfl(sl, j) * HID + lane];
    }
    acc += di * di * h1c[slot1[i] * HID + lane];
    smA[wv][lane] = acc;  // same-wave write->read (lockstep)
    float v = b2[lane];
#pragma unroll 16
    for (int k = 0; k < HID; ++k) v += smA[wv][k] * W2[k * HID + lane];
    v = v > 0.f ? v : 0.f;
    if (w < 64) h2s[w][lane] = v; else h2c[w * HID + lane] = v;
  }
  __syncthreads();

  float dn = 1.0f / sqrtf((float)(deg[nidx] + 1));
  int cnt = min(*ec3, CL3);
  float acc = 0.f;
  for (int j0 = 0; j0 < cnt; j0 += 64) {
    int nb = min(64, cnt - j0);
    if (tid < nb) {
      int s = l3[j0 + tid];
      ssl[tid] = slot2[s];
      scc[tid] = (1.0f / sqrtf((float)(deg[s] + 1))) * dn;
    }
    __syncthreads();
    for (int j = wv; j < nb; j += 4) {
      int r = ssl[j];
      float hv = (r < 64) ? h2s[r][lane] : h2c[r * HID + lane];
      acc += scc[j] * hv;
    }
    __syncthreads();
  }
  smA[wv][lane] = acc;
  __syncthreads();
  if (wv == 0) {
    int r = slot2[nidx];
    float hv = (r < 64) ? h2s[r][lane] : h2c[r * HID + lane];
    g3[lane] = smA[0][lane] + smA[1][lane] + smA[2][lane] + smA[3][lane] +
               dn * dn * hv;
  }
  __syncthreads();
  if (wv == 0) {
    float v = b3[lane];
#pragma unroll 16
    for (int k = 0; k < HID; ++k) v += g3[k] * W3[k * HID + lane];
    h3v[lane] = v > 0.f ? v : 0.f;
  }
  __syncthreads();
  if (wv == 0) {
    float v = bp[lane];
#pragma unroll 16
    for (int k = 0; k < HID; ++k) v += h3v[k] * Wp[k * HID + lane];
    pj[lane] = v > 0.f ? v : 0.f;
  }
  __syncthreads();
  if (tid < 4) {
    float o = ba[tid];
    for (int k = 0; k < HID; ++k) o += pj[k] * Wa[k * 4 + tid];
    out[tid] = o;
  } else if (tid < 6) {
    int c = tid - 4; float o = bm[c];
    for (int k = 0; k < HID; ++k) o += pj[k] * Wm[k * 2 + c];
    out[tid] = o;
  } else if (tid < 9) {
    int c = tid - 6; float o = bg[c];
    for (int k = 0; k < HID; ++k) o += pj[k] * Wg[k * 3 + c];
    out[tid] = o;
  } else if (tid < 19) {
    int c = tid - 9; float o = bt[c];
    for (int k = 0; k < HID; ++k) o += pj[k] * Wt[k * 10 + c];
    out[tid] = o;
  }
}

extern "C" void kernel_launch(void* const* d_in, const int* in_sizes, int n_in,
                              void* d_out, int out_size, void* d_ws, size_t ws_size,
                              hipStream_t stream) {
  const float* x  = (const float*)d_in[0];
  const void*  ei = d_in[1];
  const int* nidx = (const int*)d_in[2];
  const float* W1 = (const float*)d_in[3];
  const float* b1 = (const float*)d_in[4];
  const float* W2 = (const float*)d_in[5];
  const float* b2 = (const float*)d_in[6];
  const float* W3 = (const float*)d_in[7];
  const float* b3 = (const float*)d_in[8];
  const float* Wp = (const float*)d_in[9];
  const float* bp = (const float*)d_in[10];
  const float* Wa = (const float*)d_in[11];
  const float* ba = (const float*)d_in[12];
  const float* Wm = (const float*)d_in[13];
  const float* bm = (const float*)d_in[14];
  const float* Wg = (const float*)d_in[15];
  const float* bg = (const float*)d_in[16];
  const float* Wt = (const float*)d_in[17];
  const float* bt = (const float*)d_in[18];
  float* out = (float*)d_out;

  int N = in_sizes[0] / 4;   // 100000
  int E = in_sizes[1] / 2;   // 1600000

  char* w = (char*)d_ws;
  size_t o = 0;
  auto take = [&](size_t bytes) -> void* {
    void* p = w + o;
    o += (bytes + 255) & ~(size_t)255;
    return p;
  };
  // zero region (one memset): cnt1, cnt2, ec3, deg, need, rc1, rc2
  size_t zeroBytes = (size_t)(3 + 2 * N + CAP1 + CAP2) * 4;
  int* zr = (int*)take(zeroBytes);
  int* cnt1 = zr + 0;
  int* cnt2 = zr + 1;
  int* ec3  = zr + 2;
  int* deg  = zr + 3;
  int* need = deg + N;
  int* rc1  = need + N;
  int* rc2  = rc1 + CAP1;
  // 0xFF region (one memset): slot1, slot2  (-1 == all ones)
  int* slots = (int*)take((size_t)2 * N * 4);
  int* slot1 = slots;
  int* slot2 = slots + N;
  int*   dst32 = (int*)take((size_t)E * 4);
  int*   node1 = (int*)take((size_t)CAP1 * 4);
  int*   node2 = (int*)take((size_t)CAP2 * 4);
  int*   bl1   = (int*)take((size_t)CAP1 * RB1 * 4);
  int*   bl2   = (int*)take((size_t)CAP2 * RB2 * 4);
  int*   l3    = (int*)take((size_t)CL3 * 4);
  float* h1c   = (float*)take((size_t)CAP1 * HID * 4);
  float* h2c   = (float*)take((size_t)CAP2 * HID * 4);

  int gS = (int)(((long long)E + TPB * VE - 1) / (TPB * VE));

  hipMemsetAsync(zr, 0x00, zeroBytes, stream);
  hipMemsetAsync(slots, 0xFF, (size_t)2 * N * 4, stream);
  k_scanF1 <<<gS, TPB, 0, stream>>>(ei, E, nidx, dst32, slot2, node2, cnt2, l3, ec3);
  k_scanF2 <<<gS, TPB, 0, stream>>>(ei, E, dst32, slot2, node2, cnt2,
                                    slot1, node1, need, cnt1, rc2, bl2);
  k_scanS  <<<gS, TPB, 0, stream>>>(ei, E, dst32, slot1, need, rc1, bl1);
  k_scanDeg<<<gS, TPB, 0, stream>>>(E, dst32, need, deg);
  k_l1     <<<CAP1 / 4, TPB, 0, stream>>>(x, W1, b1, deg, node1, cnt1, rc1, bl1, h1c);
  k_l2tail <<<1, TPB, 0, stream>>>(W2, b2, deg, node2, cnt2, slot1, rc2, bl2,
                                   h1c, h2c, nidx, slot2, l3, ec3, W3, b3,
                                   Wp, bp, Wa, ba, Wm, bm, Wg, bg, Wt, bt, out);
}

// Round 5
// 172.630 us; speedup vs baseline: 4.9967x; 1.1256x over previous
//
#include <hip/hip_runtime.h>

// GCN on 100K nodes / 1.6M edges; output depends only on node_index's 3-hop
// in-neighborhood. v6 = v5 scans + v3 layer kernels.
// v5 post-mortem: fusing l2+tail into ONE block serialized ~17 rows onto 4
// waves on a single CU (59us, occupancy 0.035%). v3's k_l2 gave each row its
// own wave/CU (latency parallel). Unfused here; v5's scan wins kept:
//  - detect/seed folded into scans (no k_detect/k_seed dispatches)
//  - scanF1 compacts dst low-dwords into dst32[E]; scans 2-4 read that
//    (half the bytes); scanDeg doesn't touch ei at all.
//   F1 = in(n0) u {n0}   (~17)   -> rows node2/slot2 -> h2c
//   F2 = in(F1) u F1     (~290)  -> rows node1/slot1 -> h1c
//   S  = F2 u in(F2)     (~5K)   -> need[]: degree targets
// 9 dispatches (2 memsets + 7 kernels).

#define HID  64
#define CAP1 2048   // compact rows for F2 (layer-1 outputs)
#define CAP2 512    // compact rows for F1 (layer-2 outputs)
#define RB1  128    // per-row in-edge bucket depth, layer 1
#define RB2  128    // per-row in-edge bucket depth, layer 2
#define CL3  2048   // layer-3 edge list capacity
#define VE   8      // edges per thread in scans
#define TPB  256

// wave-level dtype probe: high dwords of first 64 entries all zero -> int64
__device__ __forceinline__ int detect64(const void* ei) {
  const unsigned* e32 = (const unsigned*)ei;
  int lane = threadIdx.x & 63;
  bool z = (e32[2 * lane + 1] == 0u);
  return (__ballot(z) == ~0ull) ? 1 : 0;
}

__device__ __forceinline__ int ld_src(const void* ei, int is64, long long e) {
  return is64 ? (int)((const unsigned*)ei)[e << 1] : ((const int*)ei)[e];
}

// load up to VE dst values from the raw edge index (scanF1 only)
__device__ __forceinline__ int load_dsts(const void* ei, long long E, long long base,
                                         int is64, int d[VE]) {
  int n = (int)((E - base) < VE ? (E - base) : VE);
  if (is64) {
    const unsigned long long* p = (const unsigned long long*)ei + E + base;
    if (n == VE && (((E + base) & 1) == 0)) {
      const ulonglong2* q = (const ulonglong2*)p;
#pragma unroll
      for (int k = 0; k < VE / 2; ++k) {
        ulonglong2 v = q[k];
        d[2 * k] = (int)(unsigned)v.x; d[2 * k + 1] = (int)(unsigned)v.y;
      }
    } else {
      for (int k = 0; k < n; ++k) d[k] = (int)(unsigned)p[k];
    }
  } else {
    const int* p = (const int*)ei + E + base;
    if (n == VE && (((E + base) & 3) == 0)) {
      const int4* q = (const int4*)p;
#pragma unroll
      for (int k = 0; k < VE / 4; ++k) {
        int4 v = q[k];
        d[4 * k] = v.x; d[4 * k + 1] = v.y; d[4 * k + 2] = v.z; d[4 * k + 3] = v.w;
      }
    } else {
      for (int k = 0; k < n; ++k) d[k] = p[k];
    }
  }
  return n;
}

// load up to VE dst values from the compacted int32 array (scans 2-4)
__device__ __forceinline__ int load_dsts32(const int* dst32, long long E,
                                           long long base, int d[VE]) {
  int n = (int)((E - base) < VE ? (E - base) : VE);
  if (n == VE) {  // base is a multiple of VE -> 16B aligned
    int4 a = ((const int4*)(dst32 + base))[0];
    int4 b = ((const int4*)(dst32 + base))[1];
    d[0] = a.x; d[1] = a.y; d[2] = a.z; d[3] = a.w;
    d[4] = b.x; d[5] = b.y; d[6] = b.z; d[7] = b.w;
  } else {
    for (int k = 0; k < n; ++k) d[k] = dst32[base + k];
  }
  return n;
}

// F1 discovery (dst == n0) + n0 seeding + dst32 compaction + layer-3 list.
__global__ void k_scanF1(const void* ei, int E, const int* nidx_p, int* dst32,
                         int* slot2, int* node2, int* cnt2, int* l3, int* ec3) {
  int is64 = detect64(ei);
  int nidx = *nidx_p;
  if (blockIdx.x == 0 && threadIdx.x == 0) {  // seed n0 into F1 (CAS-safe)
    if (atomicCAS(&slot2[nidx], -1, -2) == -1) {
      int p = atomicAdd(cnt2, 1) & (CAP2 - 1);
      slot2[nidx] = p; node2[p] = nidx;
    }
  }
  long long base = ((long long)blockIdx.x * TPB + threadIdx.x) * VE;
  if (base >= E) return;
  int d[VE];
  int n = load_dsts(ei, E, base, is64, d);
  if (n == VE) {
    ((int4*)(dst32 + base))[0] = make_int4(d[0], d[1], d[2], d[3]);
    ((int4*)(dst32 + base))[1] = make_int4(d[4], d[5], d[6], d[7]);
  } else {
    for (int k = 0; k < n; ++k) dst32[base + k] = d[k];
  }
  for (int k = 0; k < n; ++k) {
    if (d[k] == nidx) {
      int s = ld_src(ei, is64, base + k);
      if (atomicCAS(&slot2[s], -1, -2) == -1) {
        int p = atomicAdd(cnt2, 1) & (CAP2 - 1);
        slot2[s] = p; node2[p] = s;
      }
      int q = atomicAdd(ec3, 1);
      if (q < CL3) l3[q] = s;
    }
  }
}

// F2 discovery: prologue propagates F1 -> slot1 (+need); main loop claims
// sources of F1-dst edges and buckets them per F1 row. slot1 values are
// never READ here, so concurrent CAS claims across blocks are safe.
__global__ void k_scanF2(const void* ei, int E, const int* dst32,
                         const int* slot2, const int* node2, const int* cnt2,
                         int* slot1, int* node1, int* need, int* cnt1,
                         int* rc2, int* bl2) {
  int rows2 = min(*cnt2, CAP2);
  for (int r = threadIdx.x; r < rows2; r += TPB) {
    int i = node2[r];
    need[i] = 1;
    if (atomicCAS(&slot1[i], -1, -2) == -1) {
      int p = atomicAdd(cnt1, 1) & (CAP1 - 1);
      slot1[i] = p; node1[p] = i;
    }
  }
  int is64 = detect64(ei);
  long long base = ((long long)blockIdx.x * TPB + threadIdx.x) * VE;
  if (base >= E) return;
  int d[VE];
  int n = load_dsts32(dst32, E, base, d);
  for (int k = 0; k < n; ++k) {
    int ad = slot2[d[k]];
    if (ad >= 0) {
      int s = ld_src(ei, is64, base + k);
      need[s] = 1;
      if (atomicCAS(&slot1[s], -1, -2) == -1) {
        int p = atomicAdd(cnt1, 1) & (CAP1 - 1);
        slot1[s] = p; node1[p] = s;
      }
      int q = atomicAdd(&rc2[ad], 1);
      if (q < RB2) bl2[ad * RB2 + q] = s;
    }
  }
}

// S marking + layer-1 buckets: edges with dst in F2.
__global__ void k_scanS(const void* ei, int E, const int* dst32,
                        const int* slot1, int* need, int* rc1, int* bl1) {
  int is64 = detect64(ei);
  long long base = ((long long)blockIdx.x * TPB + threadIdx.x) * VE;
  if (base >= E) return;
  int d[VE];
  int n = load_dsts32(dst32, E, base, d);
  for (int k = 0; k < n; ++k) {
    int ad = slot1[d[k]];
    if (ad >= 0) {
      int s = ld_src(ei, is64, base + k);
      need[s] = 1;
      int q = atomicAdd(&rc1[ad], 1);
      if (q < RB1) bl1[ad * RB1 + q] = s;
    }
  }
}

// need-filtered degree histogram (~80K atomics over ~5K addresses)
__global__ void k_scanDeg(int E, const int* dst32, const int* need, int* deg) {
  long long base = ((long long)blockIdx.x * TPB + threadIdx.x) * VE;
  if (base >= E) return;
  int d[VE];
  int n = load_dsts32(dst32, E, base, d);
  for (int k = 0; k < n; ++k)
    if (need[d[k]]) atomicAdd(&deg[d[k]], 1);
}

// layer 1, one wave per F2 row (factorized: neighbor-sum then one matvec).
__global__ void k_l1(const float* __restrict__ x, const float* __restrict__ W1,
                     const float* __restrict__ b1, const int* __restrict__ deg,
                     const int* __restrict__ node1, const int* __restrict__ cnt1,
                     const int* __restrict__ rc1, const int* __restrict__ bl1,
                     float* __restrict__ h1c) {
  int w = blockIdx.x * 4 + (threadIdx.x >> 6);
  int lane = threadIdx.x & 63;
  int rows = min(*cnt1, CAP1);
  if (w >= rows) return;
  int i = node1[w];
  float di = 1.0f / sqrtf((float)(deg[i] + 1));
  int cnt = min(rc1[w], RB1);
  float ax = 0.f, ay = 0.f, az = 0.f, aw = 0.f;
  for (int j = lane; j < cnt; j += 64) {
    int s = bl1[w * RB1 + j];
    float c = (1.0f / sqrtf((float)(deg[s] + 1))) * di;
    float4 xv = ((const float4*)x)[s];
    ax += c * xv.x; ay += c * xv.y; az += c * xv.z; aw += c * xv.w;
  }
#pragma unroll
  for (int t = 1; t < 64; t <<= 1) {
    ax += __shfl_xor(ax, t); ay += __shfl_xor(ay, t);
    az += __shfl_xor(az, t); aw += __shfl_xor(aw, t);
  }
  float4 xi = ((const float4*)x)[i];
  float dd = di * di;
  ax += dd * xi.x; ay += dd * xi.y; az += dd * xi.z; aw += dd * xi.w;
  float v = ax * W1[lane] + ay * W1[64 + lane] + az * W1[128 + lane] +
            aw * W1[192 + lane] + b1[lane];
  h1c[w * HID + lane] = v > 0.f ? v : 0.f;
}

// layer 2, one wave per F1 row (each active row gets its own CU).
__global__ void k_l2(const float* __restrict__ W2, const float* __restrict__ b2,
                     const int* __restrict__ deg, const int* __restrict__ node2,
                     const int* __restrict__ cnt2, const int* __restrict__ slot1,
                     const int* __restrict__ rc2, const int* __restrict__ bl2,
                     const float* __restrict__ h1c, float* __restrict__ h2c) {
  __shared__ float sh[4][HID];
  int wv = threadIdx.x >> 6, lane = threadIdx.x & 63;
  int w = blockIdx.x * 4 + wv;
  int rows = min(*cnt2, CAP2);
  if (w >= rows) return;
  int i = node2[w];
  float di = 1.0f / sqrtf((float)(deg[i] + 1));
  int cnt = min(rc2[w], RB2);
  float acc = 0.f;
  for (int j0 = 0; j0 < cnt; j0 += 64) {
    int nb = min(64, cnt - j0);
    int sl = 0; float c = 0.f;
    if (lane < nb) {
      int s = bl2[w * RB2 + j0 + lane];
      sl = slot1[s];
      c = (1.0f / sqrtf((float)(deg[s] + 1))) * di;
    }
    for (int j = 0; j < nb; ++j) {
      int slj = __shfl(sl, j);
      float cj = __shfl(c, j);
      acc += cj * h1c[slj * HID + lane];
    }
  }
  acc += di * di * h1c[slot1[i] * HID + lane];
  sh[wv][lane] = acc;  // same-wave write->read (lockstep), no barrier needed
  float v = b2[lane];
#pragma unroll 16
  for (int k = 0; k < HID; ++k) v += sh[wv][k] * W2[k * HID + lane];
  h2c[w * HID + lane] = v > 0.f ? v : 0.f;
}

// layer-3 aggregate (factorized) + head MLP + 4 projections. One block.
__global__ void k_tail(const int* nidx_p, const int* slot2, const int* deg,
                       const float* h2c, const int* l3, const int* ec3,
                       const float* W3, const float* b3,
                       const float* Wp, const float* bp,
                       const float* Wa, const float* ba,
                       const float* Wm, const float* bm,
                       const float* Wg, const float* bg,
                       const float* Wt, const float* bt, float* out) {
  __shared__ float part[4][HID];
  __shared__ float g3[HID];
  __shared__ float h3[HID];
  __shared__ float p[HID];
  __shared__ int   ssl[64];
  __shared__ float scc[64];
  int tid = threadIdx.x, wv = tid >> 6, lane = tid & 63;
  int nidx = *nidx_p;
  float dn = 1.0f / sqrtf((float)(deg[nidx] + 1));
  int cnt = min(*ec3, CL3);
  float acc = 0.f;
  for (int j0 = 0; j0 < cnt; j0 += 64) {
    int nb = min(64, cnt - j0);
    if (tid < nb) {
      int s = l3[j0 + tid];
      ssl[tid] = slot2[s];
      scc[tid] = (1.0f / sqrtf((float)(deg[s] + 1))) * dn;
    }
    __syncthreads();
    for (int j = wv; j < nb; j += 4)
      acc += scc[j] * h2c[ssl[j] * HID + lane];
    __syncthreads();
  }
  part[wv][lane] = acc;
  __syncthreads();
  if (wv == 0) {
    float a = part[0][lane] + part[1][lane] + part[2][lane] + part[3][lane];
    a += dn * dn * h2c[slot2[nidx] * HID + lane];
    g3[lane] = a;
  }
  __syncthreads();
  if (wv == 0) {
    float v = b3[lane];
#pragma unroll 16
    for (int k = 0; k < HID; ++k) v += g3[k] * W3[k * HID + lane];
    h3[lane] = v > 0.f ? v : 0.f;
  }
  __syncthreads();
  if (wv == 0) {
    float pv = bp[lane];
#pragma unroll 16
    for (int k = 0; k < HID; ++k) pv += h3[k] * Wp[k * HID + lane];
    p[lane] = pv > 0.f ? pv : 0.f;
  }
  __syncthreads();
  if (tid < 4) {
    float o = ba[tid];
    for (int k = 0; k < HID; ++k) o += p[k] * Wa[k * 4 + tid];
    out[tid] = o;
  } else if (tid < 6) {
    int c = tid - 4; float o = bm[c];
    for (int k = 0; k < HID; ++k) o += p[k] * Wm[k * 2 + c];
    out[tid] = o;
  } else if (tid < 9) {
    int c = tid - 6; float o = bg[c];
    for (int k = 0; k < HID; ++k) o += p[k] * Wg[k * 3 + c];
    out[tid] = o;
  } else if (tid < 19) {
    int c = tid - 9; float o = bt[c];
    for (int k = 0; k < HID; ++k) o += p[k] * Wt[k * 10 + c];
    out[tid] = o;
  }
}

extern "C" void kernel_launch(void* const* d_in, const int* in_sizes, int n_in,
                              void* d_out, int out_size, void* d_ws, size_t ws_size,
                              hipStream_t stream) {
  const float* x  = (const float*)d_in[0];
  const void*  ei = d_in[1];
  const int* nidx = (const int*)d_in[2];
  const float* W1 = (const float*)d_in[3];
  const float* b1 = (const float*)d_in[4];
  const float* W2 = (const float*)d_in[5];
  const float* b2 = (const float*)d_in[6];
  const float* W3 = (const float*)d_in[7];
  const float* b3 = (const float*)d_in[8];
  const float* Wp = (const float*)d_in[9];
  const float* bp = (const float*)d_in[10];
  const float* Wa = (const float*)d_in[11];
  const float* ba = (const float*)d_in[12];
  const float* Wm = (const float*)d_in[13];
  const float* bm = (const float*)d_in[14];
  const float* Wg = (const float*)d_in[15];
  const float* bg = (const float*)d_in[16];
  const float* Wt = (const float*)d_in[17];
  const float* bt = (const float*)d_in[18];
  float* out = (float*)d_out;

  int N = in_sizes[0] / 4;   // 100000
  int E = in_sizes[1] / 2;   // 1600000

  char* w = (char*)d_ws;
  size_t o = 0;
  auto take = [&](size_t bytes) -> void* {
    void* p = w + o;
    o += (bytes + 255) & ~(size_t)255;
    return p;
  };
  // zero region (one memset): cnt1, cnt2, ec3, deg, need, rc1, rc2
  size_t zeroBytes = (size_t)(3 + 2 * N + CAP1 + CAP2) * 4;
  int* zr = (int*)take(zeroBytes);
  int* cnt1 = zr + 0;
  int* cnt2 = zr + 1;
  int* ec3  = zr + 2;
  int* deg  = zr + 3;
  int* need = deg + N;
  int* rc1  = need + N;
  int* rc2  = rc1 + CAP1;
  // 0xFF region (one memset): slot1, slot2  (-1 == all ones)
  int* slots = (int*)take((size_t)2 * N * 4);
  int* slot1 = slots;
  int* slot2 = slots + N;
  int*   dst32 = (int*)take((size_t)E * 4);
  int*   node1 = (int*)take((size_t)CAP1 * 4);
  int*   node2 = (int*)take((size_t)CAP2 * 4);
  int*   bl1   = (int*)take((size_t)CAP1 * RB1 * 4);
  int*   bl2   = (int*)take((size_t)CAP2 * RB2 * 4);
  int*   l3    = (int*)take((size_t)CL3 * 4);
  float* h1c   = (float*)take((size_t)CAP1 * HID * 4);
  float* h2c   = (float*)take((size_t)CAP2 * HID * 4);

  int gS = (int)(((long long)E + TPB * VE - 1) / (TPB * VE));

  hipMemsetAsync(zr, 0x00, zeroBytes, stream);
  hipMemsetAsync(slots, 0xFF, (size_t)2 * N * 4, stream);
  k_scanF1 <<<gS, TPB, 0, stream>>>(ei, E, nidx, dst32, slot2, node2, cnt2, l3, ec3);
  k_scanF2 <<<gS, TPB, 0, stream>>>(ei, E, dst32, slot2, node2, cnt2,
                                    slot1, node1, need, cnt1, rc2, bl2);
  k_scanS  <<<gS, TPB, 0, stream>>>(ei, E, dst32, slot1, need, rc1, bl1);
  k_scanDeg<<<gS, TPB, 0, stream>>>(E, dst32, need, deg);
  k_l1     <<<CAP1 / 4, TPB, 0, stream>>>(x, W1, b1, deg, node1, cnt1, rc1, bl1, h1c);
  k_l2     <<<CAP2 / 4, TPB, 0, stream>>>(W2, b2, deg, node2, cnt2, slot1, rc2, bl2, h1c, h2c);
  k_tail   <<<1, TPB, 0, stream>>>(nidx, slot2, deg, h2c, l3, ec3, W3, b3, Wp, bp,
                                   Wa, ba, Wm, bm, Wg, bg, Wt, bt, out);
}